// Round 15
// baseline (47.353 us; speedup 1.0000x reference)
//
#include <hip/hip_runtime.h>
#include <hip/hip_bf16.h>

// GAT layer, B=8 N=1024 IN=128 H=4 D=32. Inputs f32, OUTPUT f32.
// Base = round-13 (44.1 us). Change: per-key prefix/suffix tables in global
// (new k_expand), k_comb loses its boundary-gather loop + scan + staging.
//
// kA     : h = x@W^T via MFMA 16x16x32 bf16; epilogue s/t/e1/e2 [h][bn].
// k_rank : LDS-staged brute-force u64 rank, scatter t/idx/e1/e2 sorted.
// k_sums : raw per-chunk sums of e1*h / e2*h + chunk denominators.
// k_expand: per (b,h), expand chunk sums to per-key tables:
//          pre2t[p] = sum_{j<p} e2*h (exclusive), suf1t[p] = sum_{j>=p} e1*h
//          (inclusive), + denominator tables. [32][1025] rows of 32 floats.
// k_comb : stage tS, search once per query group, out =
//          (A*suf1t[p] + B*pre2t[p]) / (A*dsuf1t[p] + B*dpre2t[p]).

#define B_   8
#define N_   1024
#define BN   (B_ * N_)
#define IND  128
#define H_   4
#define D_   32
#define NEG  0.2f
#define CH   16
#define NCH  (N_ / CH)       // 64
#define QB   64              // queries per k_comb block
#define TROWS (N_ + 1)       // 1025 table rows per (b,h)

typedef float float4_ __attribute__((ext_vector_type(4)));
typedef short short8_ __attribute__((ext_vector_type(8)));

__device__ __forceinline__ float bf2f(ushort u) {
    union { unsigned int i; float f; } v; v.i = ((unsigned int)u) << 16; return v.f;
}
__device__ __forceinline__ ushort f2bf(float f) {
    union { float f; unsigned int i; } v; v.f = f;
    unsigned int lsb = (v.i >> 16) & 1u;
    v.i += 0x7fffu + lsb;
    return (ushort)(v.i >> 16);
}
__device__ __forceinline__ unsigned int orderable(float f) {
    unsigned int u = __float_as_uint(f);
    return (u & 0x80000000u) ? ~u : (u | 0x80000000u);
}
__device__ __forceinline__ short8_ pack_hi(float4_ a, float4_ b) {
    short8_ r;
    r[0] = (short)f2bf(a[0]); r[1] = (short)f2bf(a[1]);
    r[2] = (short)f2bf(a[2]); r[3] = (short)f2bf(a[3]);
    r[4] = (short)f2bf(b[0]); r[5] = (short)f2bf(b[1]);
    r[6] = (short)f2bf(b[2]); r[7] = (short)f2bf(b[3]);
    return r;
}
__device__ __forceinline__ void split_bf(float4_ a, float4_ b, short8_& hi, short8_& lo) {
    #pragma unroll
    for (int j = 0; j < 4; ++j) {
        ushort h0 = f2bf(a[j]); hi[j]     = (short)h0; lo[j]     = (short)f2bf(a[j] - bf2f(h0));
        ushort h1 = f2bf(b[j]); hi[j + 4] = (short)h1; lo[j + 4] = (short)f2bf(b[j] - bf2f(h1));
    }
}

// ---------------- Kernel A: MFMA GEMM + alpha epilogue --------------------
// grid = 256 blocks x 256 thr (4 waves). Block: 32 rows (2 M-tiles of 16).
__global__ __launch_bounds__(256) void k_gemm_alpha(
    const float* __restrict__ x,      // [B*N,128]
    const float* __restrict__ alive,  // [B*N]
    const float* __restrict__ W,      // [128,128]
    const float* __restrict__ a_src,  // [128]
    const float* __restrict__ a_dst,  // [128]
    float* __restrict__ h_ws,         // [B*N,128]
    float* __restrict__ sT,           // [H][BN]
    float* __restrict__ tT,           // [H][BN]
    float* __restrict__ e1T,          // [H][BN]
    float* __restrict__ e2T)          // [H][BN]
{
    __shared__ float hs[32][132];     // 16.9 KB
    __shared__ float asrc[IND], adst[IND];

    const int tid = threadIdx.x;
    const int wv  = tid >> 6;
    const int ln  = tid & 63;
    const int l15 = ln & 15;
    const int lg  = ln >> 4;
    const int rbase = blockIdx.x * 32;

    if (tid < IND) { asrc[tid] = a_src[tid]; adst[tid] = a_dst[tid]; }

    short8_ bf[2][4];
    #pragma unroll
    for (int t = 0; t < 2; ++t) {
        const float* wr = &W[(size_t)((wv * 2 + t) * 16 + l15) * IND + lg * 8];
        #pragma unroll
        for (int ks = 0; ks < 4; ++ks) {
            float4_ v0 = *reinterpret_cast<const float4_*>(wr + ks * 32);
            float4_ v1 = *reinterpret_cast<const float4_*>(wr + ks * 32 + 4);
            bf[t][ks] = pack_hi(v0, v1);
        }
    }

    float4_ acc[2][2];
    #pragma unroll
    for (int mt = 0; mt < 2; ++mt) {
        const float* xr = &x[(size_t)(rbase + mt * 16 + l15) * IND + lg * 8];
        short8_ ahi[4], alo[4];
        #pragma unroll
        for (int ks = 0; ks < 4; ++ks) {
            float4_ v0 = *reinterpret_cast<const float4_*>(xr + ks * 32);
            float4_ v1 = *reinterpret_cast<const float4_*>(xr + ks * 32 + 4);
            split_bf(v0, v1, ahi[ks], alo[ks]);
        }
        #pragma unroll
        for (int t = 0; t < 2; ++t) {
            float4_ a = {0.f, 0.f, 0.f, 0.f};
            #pragma unroll
            for (int ks = 0; ks < 4; ++ks) {
                a = __builtin_amdgcn_mfma_f32_16x16x32_bf16(ahi[ks], bf[t][ks], a, 0, 0, 0);
                a = __builtin_amdgcn_mfma_f32_16x16x32_bf16(alo[ks], bf[t][ks], a, 0, 0, 0);
            }
            acc[mt][t] = a;
        }
    }

    #pragma unroll
    for (int mt = 0; mt < 2; ++mt)
        #pragma unroll
        for (int t = 0; t < 2; ++t) {
            const int col = (wv * 2 + t) * 16 + l15;
            #pragma unroll
            for (int r = 0; r < 4; ++r)
                hs[mt * 16 + lg * 4 + r][col] = acc[mt][t][r];
        }
    __syncthreads();

    #pragma unroll
    for (int i = tid; i < 1024; i += 256) {
        int row = i >> 5, c4 = (i & 31) * 4;
        *reinterpret_cast<float4_*>(&h_ws[(size_t)(rbase + row) * IND + c4]) =
            *reinterpret_cast<const float4_*>(&hs[row][c4]);
    }

    if (tid < 128) {
        const int row = tid >> 2, hh = tid & 3;
        const float* hr = &hs[row][hh * 32];
        float s = 0.f, tt = 0.f;
        #pragma unroll
        for (int d = 0; d < 32; ++d) {
            s  = fmaf(hr[d], asrc[hh * 32 + d], s);
            tt = fmaf(hr[d], adst[hh * 32 + d], tt);
        }
        const int grow = rbase + row;
        const int idx  = hh * BN + grow;
        sT[idx] = s;
        tT[idx] = tt;
        float am = (alive[grow] >= 0.5f) ? 1.f : 0.f;
        e1T[idx] = am * __expf(tt);
        e2T[idx] = am * __expf(NEG * tt);
    }
}

// ---------------- Kernel 2: LDS-staged rank + scatter ---------------------
// grid = (4, H, B), 256 threads.
__global__ __launch_bounds__(256) void k_rank(
    const float* __restrict__ tT,
    const float* __restrict__ e1T,
    const float* __restrict__ e2T,
    float* __restrict__ tSg,   // [32][N]
    int*   __restrict__ kIg,
    float* __restrict__ e1g,
    float* __restrict__ e2g)
{
    __shared__ unsigned long long keys[N_];   // 8 KB
    const int h = blockIdx.y, b = blockIdx.z;
    const int base = h * BN + b * N_;
    for (int i = threadIdx.x; i < N_; i += 256) {
        unsigned int u = orderable(tT[base + i]);
        keys[i] = ((unsigned long long)u << 32) | (unsigned int)i;
    }
    __syncthreads();

    const int i0 = blockIdx.x * 256 + threadIdx.x;
    const unsigned long long mk = keys[i0];
    int rank = 0;
    const ulonglong2* k2p = reinterpret_cast<const ulonglong2*>(keys);
    #pragma unroll 8
    for (int j = 0; j < N_ / 2; ++j) {
        ulonglong2 kk = k2p[j];
        rank += (int)(kk.x < mk) + (int)(kk.y < mk);
    }
    const int o = (b * H_ + h) * N_ + rank;
    tSg[o] = tT[base + i0];
    kIg[o] = i0;
    e1g[o] = e1T[base + i0];
    e2g[o] = e2T[base + i0];
}

// ---------------- Kernel 3: raw chunk sums (no scan) ----------------------
// grid = (H, B, 4), 256 threads. Block covers 16 chunks (256 sorted keys).
__global__ __launch_bounds__(256) void k_sums(
    const float* __restrict__ h_ws,
    const int*   __restrict__ kIg,
    const float* __restrict__ e1g,
    const float* __restrict__ e2g,
    float* __restrict__ pre2r,   // [32][64][32]
    float* __restrict__ suf1r,   // [32][64][32]
    float* __restrict__ dpre2r,  // [32][64]
    float* __restrict__ dsuf1r)  // [32][64]
{
    __shared__ int   kI[256];
    __shared__ float e1S[256], e2S[256];

    const int h = blockIdx.x, b = blockIdx.y, cz = blockIdx.z;
    const int bhi = b * H_ + h;
    const int so  = bhi * N_ + cz * 256;
    const int tid = threadIdx.x;

    kI[tid]  = kIg[so + tid];
    e1S[tid] = e1g[so + tid];
    e2S[tid] = e2g[so + tid];
    __syncthreads();

    const int half = tid & 1, dg = (tid >> 1) & 7, cc = tid >> 4;
    float4_ a1 = {0.f, 0.f, 0.f, 0.f}, a2 = {0.f, 0.f, 0.f, 0.f};
    float d1 = 0.f, d2 = 0.f;
    #pragma unroll
    for (int jj = 0; jj < 8; ++jj) {
        const int j = cc * CH + half * 8 + jj;
        const float4_ hv = *reinterpret_cast<const float4_*>(
            &h_ws[(size_t)(b * N_ + kI[j]) * IND + h * D_ + dg * 4]);
        a1 += e1S[j] * hv;
        a2 += e2S[j] * hv;
        d1 += e1S[j];
        d2 += e2S[j];
    }
    #pragma unroll
    for (int u = 0; u < 4; ++u) {
        a1[u] += __shfl_xor(a1[u], 1);
        a2[u] += __shfl_xor(a2[u], 1);
    }
    d1 += __shfl_xor(d1, 1);
    d2 += __shfl_xor(d2, 1);

    if (!half) {
        const int gcc = cz * 16 + cc;
        *reinterpret_cast<float4_*>(&pre2r[(bhi * NCH + gcc) * D_ + dg * 4]) = a2;
        *reinterpret_cast<float4_*>(&suf1r[(bhi * NCH + gcc) * D_ + dg * 4]) = a1;
        if (dg == 0) {
            dpre2r[bhi * NCH + gcc] = d2;
            dsuf1r[bhi * NCH + gcc] = d1;
        }
    }
}

// ---------------- Kernel 4: expand chunk sums to per-key tables -----------
// grid = (H, B, 8), 64 threads (1 wave). Block handles 8 chunks (128 keys).
// Lane = (chunk-local cl = tid>>3, dim-group dg = tid&7).
__global__ __launch_bounds__(64) void k_expand(
    const float* __restrict__ h_ws,
    const int*   __restrict__ kIg,
    const float* __restrict__ e1g,
    const float* __restrict__ e2g,
    const float* __restrict__ pre2r,
    const float* __restrict__ suf1r,
    const float* __restrict__ dpre2r,
    const float* __restrict__ dsuf1r,
    float* __restrict__ pre2t,   // [32][1025][32]
    float* __restrict__ suf1t,   // [32][1025][32]
    float* __restrict__ dpre2t,  // [32][1025]
    float* __restrict__ dsuf1t)  // [32][1025]
{
    __shared__ float preC[NCH][D_];   // 8 KB
    __shared__ float sufC[NCH][D_];   // 8 KB
    __shared__ float dpreC[NCH], dsufC[NCH];

    const int h = blockIdx.x, b = blockIdx.y, cz = blockIdx.z;
    const int bhi = b * H_ + h;
    const int so  = bhi * N_;
    const int tid = threadIdx.x;

    {   // stage chunk tables (coalesced float4)
        const float4_* s2 = reinterpret_cast<const float4_*>(pre2r + (size_t)bhi * NCH * D_);
        const float4_* s1 = reinterpret_cast<const float4_*>(suf1r + (size_t)bhi * NCH * D_);
        float4_* d2 = reinterpret_cast<float4_*>(&preC[0][0]);
        float4_* d1 = reinterpret_cast<float4_*>(&sufC[0][0]);
        #pragma unroll
        for (int i = tid; i < NCH * D_ / 4; i += 64) { d2[i] = s2[i]; d1[i] = s1[i]; }
        if (tid < NCH) { dpreC[tid] = dpre2r[bhi * NCH + tid]; dsufC[tid] = dsuf1r[bhi * NCH + tid]; }
    }
    __syncthreads();

    const int cl = tid >> 3;          // 0..7
    const int dg = tid & 7;
    const int c  = cz * 8 + cl;       // global chunk 0..63

    // chunk offsets: predicated uniform loop over all 64 chunks
    float4_ off2 = {0.f, 0.f, 0.f, 0.f}, off1 = {0.f, 0.f, 0.f, 0.f};
    float doff2 = 0.f, doff1 = 0.f;
    for (int cc = 0; cc < NCH; ++cc) {
        const float4_ p4 = *reinterpret_cast<const float4_*>(&preC[cc][dg * 4]);
        const float4_ s4 = *reinterpret_cast<const float4_*>(&sufC[cc][dg * 4]);
        if (cc < c) { off2 += p4; doff2 += dpreC[cc]; }
        if (cc > c) { off1 += s4; doff1 += dsufC[cc]; }
    }

    const size_t trow = (size_t)bhi * TROWS;

    // forward: exclusive prefix of e2*h (gathers cached in hv[])
    float4_ hv[16];
    float w1v[16];
    float4_ run = off2; float drun = doff2;
    #pragma unroll
    for (int k = 0; k < 16; ++k) {
        const int j = c * CH + k;
        const int ki = kIg[so + j];
        hv[k]  = *reinterpret_cast<const float4_*>(
            &h_ws[(size_t)(b * N_ + ki) * IND + h * D_ + dg * 4]);
        const float w2 = e2g[so + j];
        w1v[k] = e1g[so + j];
        *reinterpret_cast<float4_*>(&pre2t[(trow + j) * D_ + dg * 4]) = run;
        if (dg == 0) dpre2t[trow + j] = drun;
        run  += w2 * hv[k];
        drun += w2;
    }
    if (c == NCH - 1) {   // row N_ = totals / zeros
        *reinterpret_cast<float4_*>(&pre2t[(trow + N_) * D_ + dg * 4]) = run;
        float4_ z = {0.f, 0.f, 0.f, 0.f};
        *reinterpret_cast<float4_*>(&suf1t[(trow + N_) * D_ + dg * 4]) = z;
        if (dg == 0) { dpre2t[trow + N_] = drun; dsuf1t[trow + N_] = 0.f; }
    }

    // backward: inclusive suffix of e1*h (no gathers, hv cached)
    float4_ run1 = off1; float drun1 = doff1;
    #pragma unroll
    for (int k = 15; k >= 0; --k) {
        const int j = c * CH + k;
        run1  += w1v[k] * hv[k];
        drun1 += w1v[k];
        *reinterpret_cast<float4_*>(&suf1t[(trow + j) * D_ + dg * 4]) = run1;
        if (dg == 0) dsuf1t[trow + j] = drun1;
    }
}

// ---------------- Kernel 5: search + table lookup per query ---------------
// grid = (N/QB, H, B), 512 threads: 64 queries x 8 dim-groups.
__global__ __launch_bounds__(512) void k_comb(
    const float* __restrict__ sT,
    const float* __restrict__ tSg,
    const float* __restrict__ pre2t,
    const float* __restrict__ suf1t,
    const float* __restrict__ dpre2t,
    const float* __restrict__ dsuf1t,
    float* __restrict__ out)
{
    __shared__ float tS[N_];

    const int h = blockIdx.y, b = blockIdx.z, qb = blockIdx.x;
    const int bhi = b * H_ + h;
    const int tid = threadIdx.x;

    for (int i = tid; i < N_; i += 512) tS[i] = tSg[bhi * N_ + i];
    __syncthreads();

    const int ql  = tid >> 3;
    const int sub = tid & 7;
    const int ln  = tid & 63;
    const int q   = qb * QB + ql;

    const float s  = sT[h * BN + b * N_ + q];
    const float A  = __expf(s);
    const float Bv = __expf(NEG * s);

    // binary search once per query group (lane sub==0), broadcast via shfl
    int p = 0;
    if (sub == 0) {
        const float tau = -s;
        int lo = 0, hi = N_;
        #pragma unroll
        for (int it = 0; it < 10; ++it) {
            int mid = (lo + hi) >> 1;
            if (tS[mid] >= tau) hi = mid; else lo = mid + 1;
        }
        p = lo;
    }
    p = __shfl(p, ln & 56);

    const size_t trow = (size_t)bhi * TROWS + p;
    const float4_ suf = *reinterpret_cast<const float4_*>(&suf1t[trow * D_ + sub * 4]);
    const float4_ pre = *reinterpret_cast<const float4_*>(&pre2t[trow * D_ + sub * 4]);
    const float den = A * dsuf1t[trow] + Bv * dpre2t[trow];
    const float inv = (den > 0.f) ? 1.f / den : 0.f;
    float4_ r = (A * suf + Bv * pre) * inv;
    *reinterpret_cast<float4_*>(&out[(size_t)(b * N_ + q) * IND + h * D_ + sub * 4]) = r;
}

extern "C" void kernel_launch(void* const* d_in, const int* in_sizes, int n_in,
                              void* d_out, int out_size, void* d_ws, size_t ws_size,
                              hipStream_t stream) {
    const float* x     = (const float*)d_in[0];
    const float* alive = (const float*)d_in[1];
    const float* W     = (const float*)d_in[2];
    const float* a_src = (const float*)d_in[3];
    const float* a_dst = (const float*)d_in[4];
    float* out = (float*)d_out;

    float* h_ws   = (float*)d_ws;               // BN*128
    float* sT     = h_ws + (size_t)BN * IND;    // [H][BN]
    float* tT     = sT  + (size_t)H_ * BN;
    float* e1T    = tT  + (size_t)H_ * BN;
    float* e2T    = e1T + (size_t)H_ * BN;
    float* tSg    = e2T + (size_t)H_ * BN;      // [32][N]
    int*   kIg    = (int*)(tSg + 32 * N_);
    float* e1g    = (float*)(kIg + 32 * N_);
    float* e2g    = e1g + 32 * N_;
    float* pre2r  = e2g + 32 * N_;              // [32][64][32]
    float* suf1r  = pre2r + 32 * NCH * D_;
    float* dpre2r = suf1r + 32 * NCH * D_;      // [32][64]
    float* dsuf1r = dpre2r + 32 * NCH;
    float* pre2t  = dsuf1r + 32 * NCH;          // [32][1025][32]
    float* suf1t  = pre2t + (size_t)32 * TROWS * D_;
    float* dpre2t = suf1t + (size_t)32 * TROWS * D_;   // [32][1025]
    float* dsuf1t = dpre2t + (size_t)32 * TROWS;       // total ~14.5 MB

    k_gemm_alpha<<<BN / 32, 256, 0, stream>>>(x, alive, W, a_src, a_dst,
                                              h_ws, sT, tT, e1T, e2T);

    dim3 g2(N_ / 256, H_, B_);
    k_rank<<<g2, 256, 0, stream>>>(tT, e1T, e2T, tSg, kIg, e1g, e2g);

    dim3 g3(H_, B_, 4);
    k_sums<<<g3, 256, 0, stream>>>(h_ws, kIg, e1g, e2g,
                                   pre2r, suf1r, dpre2r, dsuf1r);

    dim3 g3b(H_, B_, 8);
    k_expand<<<g3b, 64, 0, stream>>>(h_ws, kIg, e1g, e2g,
                                     pre2r, suf1r, dpre2r, dsuf1r,
                                     pre2t, suf1t, dpre2t, dsuf1t);

    dim3 g4(N_ / QB, H_, B_);
    k_comb<<<g4, 512, 0, stream>>>(sT, tSg, pre2t, suf1t, dpre2t, dsuf1t, out);
}

// Round 17
// 42.652 us; speedup vs baseline: 1.1102x; 1.1102x over previous
//
#include <hip/hip_runtime.h>
#include <hip/hip_bf16.h>

// GAT layer, B=8 N=1024 IN=128 H=4 D=32. Inputs f32, OUTPUT f32.
// Base = round-13 (44.1 us best). R16's cooperative fusion failed graph
// capture (pre-declared risk) -> reverted. Single change vs R13: k_sums
// FUSED into k_comb (512 threads = 512 chunk-sum cells computed in-block,
// directly into the LDS scan tables). 3 dispatches instead of 4; the
// pre2r/suf1r global round-trip is gone.
//
// kA    : h = x@W^T via MFMA 16x16x32 bf16 (x split hi+lo bf16; W bf16).
//         Epilogue: s/t/e1/e2 per (row,head) transposed [h][bn].
// k_rank: LDS-staged brute-force u64 rank, scatter t/idx/e1/e2 sorted.
// k_comb: stages sorted arrays, computes chunk sums in-block (1 cell/thread),
//         8-wave shuffle scan, then per query: search once per 8-lane group
//         + uniform 16-iter boundary-chunk combine (weight select).

#define B_   8
#define N_   1024
#define BN   (B_ * N_)
#define IND  128
#define H_   4
#define D_   32
#define NEG  0.2f
#define CH   16
#define NCH  (N_ / CH)       // 64
#define QB   64              // queries per k_comb block

typedef float float4_ __attribute__((ext_vector_type(4)));
typedef short short8_ __attribute__((ext_vector_type(8)));

__device__ __forceinline__ float bf2f(ushort u) {
    union { unsigned int i; float f; } v; v.i = ((unsigned int)u) << 16; return v.f;
}
__device__ __forceinline__ ushort f2bf(float f) {
    union { float f; unsigned int i; } v; v.f = f;
    unsigned int lsb = (v.i >> 16) & 1u;
    v.i += 0x7fffu + lsb;
    return (ushort)(v.i >> 16);
}
__device__ __forceinline__ unsigned int orderable(float f) {
    unsigned int u = __float_as_uint(f);
    return (u & 0x80000000u) ? ~u : (u | 0x80000000u);
}
__device__ __forceinline__ short8_ pack_hi(float4_ a, float4_ b) {
    short8_ r;
    r[0] = (short)f2bf(a[0]); r[1] = (short)f2bf(a[1]);
    r[2] = (short)f2bf(a[2]); r[3] = (short)f2bf(a[3]);
    r[4] = (short)f2bf(b[0]); r[5] = (short)f2bf(b[1]);
    r[6] = (short)f2bf(b[2]); r[7] = (short)f2bf(b[3]);
    return r;
}
__device__ __forceinline__ void split_bf(float4_ a, float4_ b, short8_& hi, short8_& lo) {
    #pragma unroll
    for (int j = 0; j < 4; ++j) {
        ushort h0 = f2bf(a[j]); hi[j]     = (short)h0; lo[j]     = (short)f2bf(a[j] - bf2f(h0));
        ushort h1 = f2bf(b[j]); hi[j + 4] = (short)h1; lo[j + 4] = (short)f2bf(b[j] - bf2f(h1));
    }
}

// ---------------- Kernel A: MFMA GEMM + alpha epilogue --------------------
// grid = 256 blocks x 256 thr (4 waves). Block: 32 rows (2 M-tiles of 16).
__global__ __launch_bounds__(256) void k_gemm_alpha(
    const float* __restrict__ x,      // [B*N,128]
    const float* __restrict__ alive,  // [B*N]
    const float* __restrict__ W,      // [128,128]
    const float* __restrict__ a_src,  // [128]
    const float* __restrict__ a_dst,  // [128]
    float* __restrict__ h_ws,         // [B*N,128]
    float* __restrict__ sT,           // [H][BN]
    float* __restrict__ tT,           // [H][BN]
    float* __restrict__ e1T,          // [H][BN]
    float* __restrict__ e2T)          // [H][BN]
{
    __shared__ float hs[32][132];     // 16.9 KB
    __shared__ float asrc[IND], adst[IND];

    const int tid = threadIdx.x;
    const int wv  = tid >> 6;
    const int ln  = tid & 63;
    const int l15 = ln & 15;
    const int lg  = ln >> 4;
    const int rbase = blockIdx.x * 32;

    if (tid < IND) { asrc[tid] = a_src[tid]; adst[tid] = a_dst[tid]; }

    short8_ bf[2][4];
    #pragma unroll
    for (int t = 0; t < 2; ++t) {
        const float* wr = &W[(size_t)((wv * 2 + t) * 16 + l15) * IND + lg * 8];
        #pragma unroll
        for (int ks = 0; ks < 4; ++ks) {
            float4_ v0 = *reinterpret_cast<const float4_*>(wr + ks * 32);
            float4_ v1 = *reinterpret_cast<const float4_*>(wr + ks * 32 + 4);
            bf[t][ks] = pack_hi(v0, v1);
        }
    }

    float4_ acc[2][2];
    #pragma unroll
    for (int mt = 0; mt < 2; ++mt) {
        const float* xr = &x[(size_t)(rbase + mt * 16 + l15) * IND + lg * 8];
        short8_ ahi[4], alo[4];
        #pragma unroll
        for (int ks = 0; ks < 4; ++ks) {
            float4_ v0 = *reinterpret_cast<const float4_*>(xr + ks * 32);
            float4_ v1 = *reinterpret_cast<const float4_*>(xr + ks * 32 + 4);
            split_bf(v0, v1, ahi[ks], alo[ks]);
        }
        #pragma unroll
        for (int t = 0; t < 2; ++t) {
            float4_ a = {0.f, 0.f, 0.f, 0.f};
            #pragma unroll
            for (int ks = 0; ks < 4; ++ks) {
                a = __builtin_amdgcn_mfma_f32_16x16x32_bf16(ahi[ks], bf[t][ks], a, 0, 0, 0);
                a = __builtin_amdgcn_mfma_f32_16x16x32_bf16(alo[ks], bf[t][ks], a, 0, 0, 0);
            }
            acc[mt][t] = a;
        }
    }

    #pragma unroll
    for (int mt = 0; mt < 2; ++mt)
        #pragma unroll
        for (int t = 0; t < 2; ++t) {
            const int col = (wv * 2 + t) * 16 + l15;
            #pragma unroll
            for (int r = 0; r < 4; ++r)
                hs[mt * 16 + lg * 4 + r][col] = acc[mt][t][r];
        }
    __syncthreads();

    #pragma unroll
    for (int i = tid; i < 1024; i += 256) {
        int row = i >> 5, c4 = (i & 31) * 4;
        *reinterpret_cast<float4_*>(&h_ws[(size_t)(rbase + row) * IND + c4]) =
            *reinterpret_cast<const float4_*>(&hs[row][c4]);
    }

    if (tid < 128) {
        const int row = tid >> 2, hh = tid & 3;
        const float* hr = &hs[row][hh * 32];
        float s = 0.f, tt = 0.f;
        #pragma unroll
        for (int d = 0; d < 32; ++d) {
            s  = fmaf(hr[d], asrc[hh * 32 + d], s);
            tt = fmaf(hr[d], adst[hh * 32 + d], tt);
        }
        const int grow = rbase + row;
        const int idx  = hh * BN + grow;
        sT[idx] = s;
        tT[idx] = tt;
        float am = (alive[grow] >= 0.5f) ? 1.f : 0.f;
        e1T[idx] = am * __expf(tt);
        e2T[idx] = am * __expf(NEG * tt);
    }
}

// ---------------- Kernel 2: LDS-staged rank + scatter ---------------------
// grid = (4, H, B), 256 threads. Keys staged in LDS (8 KB); broadcast
// ds_read_b128 loop computes rank (R8-proven lean loop).
__global__ __launch_bounds__(256) void k_rank(
    const float* __restrict__ tT,
    const float* __restrict__ e1T,
    const float* __restrict__ e2T,
    float* __restrict__ tSg,   // [32][N]
    int*   __restrict__ kIg,
    float* __restrict__ e1g,
    float* __restrict__ e2g)
{
    __shared__ unsigned long long keys[N_];   // 8 KB
    const int h = blockIdx.y, b = blockIdx.z;
    const int base = h * BN + b * N_;
    for (int i = threadIdx.x; i < N_; i += 256) {
        unsigned int u = orderable(tT[base + i]);
        keys[i] = ((unsigned long long)u << 32) | (unsigned int)i;
    }
    __syncthreads();

    const int i0 = blockIdx.x * 256 + threadIdx.x;
    const unsigned long long mk = keys[i0];
    int rank = 0;
    const ulonglong2* k2p = reinterpret_cast<const ulonglong2*>(keys);
    #pragma unroll 8
    for (int j = 0; j < N_ / 2; ++j) {
        ulonglong2 kk = k2p[j];
        rank += (int)(kk.x < mk) + (int)(kk.y < mk);
    }
    const int o = (b * H_ + h) * N_ + rank;
    tSg[o] = tT[base + i0];
    kIg[o] = i0;
    e1g[o] = e1T[base + i0];
    e2g[o] = e2T[base + i0];
}

// ---------------- Kernel 3: sums + scan + per-query combine ---------------
// grid = (N/QB, H, B), 512 threads: 64 queries x 8 dim-groups.
// Chunk sums computed IN-BLOCK (1 cell/thread), replacing the k_sums kernel.
__global__ __launch_bounds__(512) void k_comb(
    const float* __restrict__ h_ws,
    const float* __restrict__ sT,
    const float* __restrict__ tSg,
    const int*   __restrict__ kIg,
    const float* __restrict__ e1g,
    const float* __restrict__ e2g,
    float* __restrict__ out)
{
    __shared__ float tS[N_];
    __shared__ int   kI[N_];
    __shared__ float e1S[N_], e2S[N_];
    __shared__ float pre2[NCH + 1][36];
    __shared__ float suf1[NCH + 2][36];
    __shared__ float dpre2[NCH + 1], dsuf1[NCH + 2];

    const int h = blockIdx.y, b = blockIdx.z, qb = blockIdx.x;
    const int bhi = b * H_ + h;
    const int so  = bhi * N_;
    const int tid = threadIdx.x;

    for (int i = tid; i < N_; i += 512) {
        tS[i]  = tSg[so + i];
        kI[i]  = kIg[so + i];
        e1S[i] = e1g[so + i];
        e2S[i] = e2g[so + i];
    }
    __syncthreads();

    // chunk sums in-block: 512 threads = 512 cells (cc 0..63, dg 0..7)
    {
        const int cc = tid >> 3, dg = tid & 7;
        float4_ a1 = {0.f, 0.f, 0.f, 0.f}, a2 = {0.f, 0.f, 0.f, 0.f};
        #pragma unroll
        for (int jj = 0; jj < CH; ++jj) {
            const int j = cc * CH + jj;
            const float4_ hv = *reinterpret_cast<const float4_*>(
                &h_ws[(size_t)(b * N_ + kI[j]) * IND + h * D_ + dg * 4]);
            a1 += e1S[j] * hv;
            a2 += e2S[j] * hv;
        }
        #pragma unroll
        for (int u = 0; u < 4; ++u) {
            pre2[cc + 1][dg * 4 + u] = a2[u];
            suf1[cc][dg * 4 + u]     = a1[u];
        }
        if (tid < NCH) {
            float s2 = 0.f;
            #pragma unroll
            for (int jj = 0; jj < CH; ++jj) s2 += e2S[tid * CH + jj];
            dpre2[tid + 1] = s2;
        } else if (tid < 2 * NCH) {
            const int c2 = tid - NCH;
            float s1 = 0.f;
            #pragma unroll
            for (int jj = 0; jj < CH; ++jj) s1 += e1S[c2 * CH + jj];
            dsuf1[c2] = s1;
        }
    }
    __syncthreads();

    // in-block scans: waves 0-3 prefix, waves 4-7 suffix
    {
        const int wv = tid >> 6, lane = tid & 63;
        if (wv < 4) {
            for (int d = wv; d < D_; d += 4) {
                float v = pre2[lane + 1][d];
                #pragma unroll
                for (int off = 1; off < 64; off <<= 1) {
                    float n = __shfl_up(v, off);
                    if (lane >= off) v += n;
                }
                pre2[lane + 1][d] = v;
                if (lane == 0) pre2[0][d] = 0.f;
            }
            if (wv == 0) {
                float v = dpre2[lane + 1];
                #pragma unroll
                for (int off = 1; off < 64; off <<= 1) {
                    float n = __shfl_up(v, off);
                    if (lane >= off) v += n;
                }
                dpre2[lane + 1] = v;
                if (lane == 0) dpre2[0] = 0.f;
            }
        } else {
            for (int d = wv - 4; d < D_; d += 4) {
                float v = suf1[lane][d];
                #pragma unroll
                for (int off = 1; off < 64; off <<= 1) {
                    float n = __shfl_down(v, off);
                    if (lane < 64 - off) v += n;
                }
                suf1[lane][d] = v;
                if (lane == 0) { suf1[NCH][d] = 0.f; suf1[NCH + 1][d] = 0.f; }
            }
            if (wv == 4) {
                float v = dsuf1[lane];
                #pragma unroll
                for (int off = 1; off < 64; off <<= 1) {
                    float n = __shfl_down(v, off);
                    if (lane < 64 - off) v += n;
                }
                dsuf1[lane] = v;
                if (lane == 0) { dsuf1[NCH] = 0.f; dsuf1[NCH + 1] = 0.f; }
            }
        }
    }
    __syncthreads();

    const int ql  = tid >> 3;
    const int sub = tid & 7;
    const int ln  = tid & 63;
    const int q   = qb * QB + ql;

    const float s  = sT[h * BN + b * N_ + q];
    const float A  = __expf(s);
    const float Bv = __expf(NEG * s);

    // binary search once per query group (lane sub==0), broadcast via shfl
    int p = 0;
    if (sub == 0) {
        const float tau = -s;
        int lo = 0, hi = N_;
        #pragma unroll
        for (int it = 0; it < 10; ++it) {
            int mid = (lo + hi) >> 1;
            if (tS[mid] >= tau) hi = mid; else lo = mid + 1;
        }
        p = lo;
    }
    p = __shfl(p, ln & 56);
    const int cp = p >> 4;

    // table part + uniform 16-iter boundary-chunk loop (weight select)
    float4_ acc = A  * (*reinterpret_cast<const float4_*>(&suf1[cp + 1][sub * 4]))
                + Bv * (*reinterpret_cast<const float4_*>(&pre2[cp][sub * 4]));
    float den = A * dsuf1[cp + 1] + Bv * dpre2[cp];
    if (cp < NCH) {
        #pragma unroll
        for (int jj = 0; jj < CH; ++jj) {
            const int j = (cp << 4) + jj;
            const float w = (j < p) ? Bv * e2S[j] : A * e1S[j];
            const float4_ hv = *reinterpret_cast<const float4_*>(
                &h_ws[(size_t)(b * N_ + kI[j]) * IND + h * D_ + sub * 4]);
            acc += w * hv;
            den += w;
        }
    }

    const float inv = (den > 0.f) ? 1.f / den : 0.f;
    float4_ r = acc * inv;
    *reinterpret_cast<float4_*>(&out[(size_t)(b * N_ + q) * IND + h * D_ + sub * 4]) = r;
}

extern "C" void kernel_launch(void* const* d_in, const int* in_sizes, int n_in,
                              void* d_out, int out_size, void* d_ws, size_t ws_size,
                              hipStream_t stream) {
    const float* x     = (const float*)d_in[0];
    const float* alive = (const float*)d_in[1];
    const float* W     = (const float*)d_in[2];
    const float* a_src = (const float*)d_in[3];
    const float* a_dst = (const float*)d_in[4];
    float* out = (float*)d_out;

    float* h_ws   = (float*)d_ws;               // BN*128
    float* sT     = h_ws + (size_t)BN * IND;    // [H][BN]
    float* tT     = sT  + (size_t)H_ * BN;
    float* e1T    = tT  + (size_t)H_ * BN;
    float* e2T    = e1T + (size_t)H_ * BN;
    float* tSg    = e2T + (size_t)H_ * BN;      // [32][N]
    int*   kIg    = (int*)(tSg + 32 * N_);
    float* e1g    = (float*)(kIg + 32 * N_);
    float* e2g    = e1g + 32 * N_;              // total ~4.9 MB

    k_gemm_alpha<<<BN / 32, 256, 0, stream>>>(x, alive, W, a_src, a_dst,
                                              h_ws, sT, tT, e1T, e2T);

    dim3 g2(N_ / 256, H_, B_);
    k_rank<<<g2, 256, 0, stream>>>(tT, e1T, e2T, tSg, kIg, e1g, e2g);

    dim3 g4(N_ / QB, H_, B_);
    k_comb<<<g4, 512, 0, stream>>>(h_ws, sT, tSg, kIg, e1g, e2g, out);
}

// Round 18
// 37.279 us; speedup vs baseline: 1.2702x; 1.1441x over previous
//
#include <hip/hip_runtime.h>
#include <hip/hip_bf16.h>

// GAT layer, B=8 N=1024 IN=128 H=4 D=32. Inputs f32, OUTPUT f32.
// Base = round-17 (42.65 us best). Single change: k_rank split-loop —
// 256 blocks x 256 thr, each key ranked by 2 threads scanning half the
// key table each (halves per-SIMD VALU issue; R10/R12 ledger shows the
// rank loop is VALU-issue-bound with 1 wave/SIMD and nothing hidden).
//
// kA    : h = x@W^T via MFMA 16x16x32 bf16 (x split hi+lo bf16; W bf16).
//         Epilogue: s/t/e1/e2 per (row,head) transposed [h][bn].
// k_rank: LDS-staged brute-force u64 rank (split across thread pairs),
//         scatter t/idx/e1/e2 sorted.
// k_comb: stages sorted arrays, computes chunk sums in-block (1 cell/thread),
//         8-wave shuffle scan, then per query: search once per 8-lane group
//         + uniform 16-iter boundary-chunk combine (weight select).

#define B_   8
#define N_   1024
#define BN   (B_ * N_)
#define IND  128
#define H_   4
#define D_   32
#define NEG  0.2f
#define CH   16
#define NCH  (N_ / CH)       // 64
#define QB   64              // queries per k_comb block

typedef float float4_ __attribute__((ext_vector_type(4)));
typedef short short8_ __attribute__((ext_vector_type(8)));

__device__ __forceinline__ float bf2f(ushort u) {
    union { unsigned int i; float f; } v; v.i = ((unsigned int)u) << 16; return v.f;
}
__device__ __forceinline__ ushort f2bf(float f) {
    union { float f; unsigned int i; } v; v.f = f;
    unsigned int lsb = (v.i >> 16) & 1u;
    v.i += 0x7fffu + lsb;
    return (ushort)(v.i >> 16);
}
__device__ __forceinline__ unsigned int orderable(float f) {
    unsigned int u = __float_as_uint(f);
    return (u & 0x80000000u) ? ~u : (u | 0x80000000u);
}
__device__ __forceinline__ short8_ pack_hi(float4_ a, float4_ b) {
    short8_ r;
    r[0] = (short)f2bf(a[0]); r[1] = (short)f2bf(a[1]);
    r[2] = (short)f2bf(a[2]); r[3] = (short)f2bf(a[3]);
    r[4] = (short)f2bf(b[0]); r[5] = (short)f2bf(b[1]);
    r[6] = (short)f2bf(b[2]); r[7] = (short)f2bf(b[3]);
    return r;
}
__device__ __forceinline__ void split_bf(float4_ a, float4_ b, short8_& hi, short8_& lo) {
    #pragma unroll
    for (int j = 0; j < 4; ++j) {
        ushort h0 = f2bf(a[j]); hi[j]     = (short)h0; lo[j]     = (short)f2bf(a[j] - bf2f(h0));
        ushort h1 = f2bf(b[j]); hi[j + 4] = (short)h1; lo[j + 4] = (short)f2bf(b[j] - bf2f(h1));
    }
}

// ---------------- Kernel A: MFMA GEMM + alpha epilogue --------------------
// grid = 256 blocks x 256 thr (4 waves). Block: 32 rows (2 M-tiles of 16).
__global__ __launch_bounds__(256) void k_gemm_alpha(
    const float* __restrict__ x,      // [B*N,128]
    const float* __restrict__ alive,  // [B*N]
    const float* __restrict__ W,      // [128,128]
    const float* __restrict__ a_src,  // [128]
    const float* __restrict__ a_dst,  // [128]
    float* __restrict__ h_ws,         // [B*N,128]
    float* __restrict__ sT,           // [H][BN]
    float* __restrict__ tT,           // [H][BN]
    float* __restrict__ e1T,          // [H][BN]
    float* __restrict__ e2T)          // [H][BN]
{
    __shared__ float hs[32][132];     // 16.9 KB
    __shared__ float asrc[IND], adst[IND];

    const int tid = threadIdx.x;
    const int wv  = tid >> 6;
    const int ln  = tid & 63;
    const int l15 = ln & 15;
    const int lg  = ln >> 4;
    const int rbase = blockIdx.x * 32;

    if (tid < IND) { asrc[tid] = a_src[tid]; adst[tid] = a_dst[tid]; }

    short8_ bf[2][4];
    #pragma unroll
    for (int t = 0; t < 2; ++t) {
        const float* wr = &W[(size_t)((wv * 2 + t) * 16 + l15) * IND + lg * 8];
        #pragma unroll
        for (int ks = 0; ks < 4; ++ks) {
            float4_ v0 = *reinterpret_cast<const float4_*>(wr + ks * 32);
            float4_ v1 = *reinterpret_cast<const float4_*>(wr + ks * 32 + 4);
            bf[t][ks] = pack_hi(v0, v1);
        }
    }

    float4_ acc[2][2];
    #pragma unroll
    for (int mt = 0; mt < 2; ++mt) {
        const float* xr = &x[(size_t)(rbase + mt * 16 + l15) * IND + lg * 8];
        short8_ ahi[4], alo[4];
        #pragma unroll
        for (int ks = 0; ks < 4; ++ks) {
            float4_ v0 = *reinterpret_cast<const float4_*>(xr + ks * 32);
            float4_ v1 = *reinterpret_cast<const float4_*>(xr + ks * 32 + 4);
            split_bf(v0, v1, ahi[ks], alo[ks]);
        }
        #pragma unroll
        for (int t = 0; t < 2; ++t) {
            float4_ a = {0.f, 0.f, 0.f, 0.f};
            #pragma unroll
            for (int ks = 0; ks < 4; ++ks) {
                a = __builtin_amdgcn_mfma_f32_16x16x32_bf16(ahi[ks], bf[t][ks], a, 0, 0, 0);
                a = __builtin_amdgcn_mfma_f32_16x16x32_bf16(alo[ks], bf[t][ks], a, 0, 0, 0);
            }
            acc[mt][t] = a;
        }
    }

    #pragma unroll
    for (int mt = 0; mt < 2; ++mt)
        #pragma unroll
        for (int t = 0; t < 2; ++t) {
            const int col = (wv * 2 + t) * 16 + l15;
            #pragma unroll
            for (int r = 0; r < 4; ++r)
                hs[mt * 16 + lg * 4 + r][col] = acc[mt][t][r];
        }
    __syncthreads();

    #pragma unroll
    for (int i = tid; i < 1024; i += 256) {
        int row = i >> 5, c4 = (i & 31) * 4;
        *reinterpret_cast<float4_*>(&h_ws[(size_t)(rbase + row) * IND + c4]) =
            *reinterpret_cast<const float4_*>(&hs[row][c4]);
    }

    if (tid < 128) {
        const int row = tid >> 2, hh = tid & 3;
        const float* hr = &hs[row][hh * 32];
        float s = 0.f, tt = 0.f;
        #pragma unroll
        for (int d = 0; d < 32; ++d) {
            s  = fmaf(hr[d], asrc[hh * 32 + d], s);
            tt = fmaf(hr[d], adst[hh * 32 + d], tt);
        }
        const int grow = rbase + row;
        const int idx  = hh * BN + grow;
        sT[idx] = s;
        tT[idx] = tt;
        float am = (alive[grow] >= 0.5f) ? 1.f : 0.f;
        e1T[idx] = am * __expf(tt);
        e2T[idx] = am * __expf(NEG * tt);
    }
}

// ---------------- Kernel 2: split-loop LDS rank + scatter -----------------
// grid = (8, H, B) = 256 blocks, 256 threads. Block owns 128 keys; each key
// is ranked by TWO threads (own = tid&127, half = tid>>7), each scanning
// half the staged table (256 ulonglong2 iters). Partials combined in LDS.
__global__ __launch_bounds__(256) void k_rank(
    const float* __restrict__ tT,
    const float* __restrict__ e1T,
    const float* __restrict__ e2T,
    float* __restrict__ tSg,   // [32][N]
    int*   __restrict__ kIg,
    float* __restrict__ e1g,
    float* __restrict__ e2g)
{
    __shared__ unsigned long long keys[N_];   // 8 KB
    __shared__ int part[128];
    const int h = blockIdx.y, b = blockIdx.z;
    const int base = h * BN + b * N_;
    for (int i = threadIdx.x; i < N_; i += 256) {
        unsigned int u = orderable(tT[base + i]);
        keys[i] = ((unsigned long long)u << 32) | (unsigned int)i;
    }
    __syncthreads();

    const int own  = threadIdx.x & 127;
    const int half = threadIdx.x >> 7;
    const int i0   = blockIdx.x * 128 + own;
    const unsigned long long mk = keys[i0];
    int rank = 0;
    const ulonglong2* k2p = reinterpret_cast<const ulonglong2*>(keys) + half * 256;
    #pragma unroll 8
    for (int j = 0; j < 256; ++j) {
        ulonglong2 kk = k2p[j];           // broadcast LDS read (wave-uniform)
        rank += (int)(kk.x < mk) + (int)(kk.y < mk);
    }
    if (half) part[own] = rank;
    __syncthreads();
    if (!half) {
        rank += part[own];
        const int o = (b * H_ + h) * N_ + rank;
        tSg[o] = tT[base + i0];
        kIg[o] = i0;
        e1g[o] = e1T[base + i0];
        e2g[o] = e2T[base + i0];
    }
}

// ---------------- Kernel 3: sums + scan + per-query combine ---------------
// grid = (N/QB, H, B), 512 threads: 64 queries x 8 dim-groups.
// Chunk sums computed IN-BLOCK (1 cell/thread).
__global__ __launch_bounds__(512) void k_comb(
    const float* __restrict__ h_ws,
    const float* __restrict__ sT,
    const float* __restrict__ tSg,
    const int*   __restrict__ kIg,
    const float* __restrict__ e1g,
    const float* __restrict__ e2g,
    float* __restrict__ out)
{
    __shared__ float tS[N_];
    __shared__ int   kI[N_];
    __shared__ float e1S[N_], e2S[N_];
    __shared__ float pre2[NCH + 1][36];
    __shared__ float suf1[NCH + 2][36];
    __shared__ float dpre2[NCH + 1], dsuf1[NCH + 2];

    const int h = blockIdx.y, b = blockIdx.z, qb = blockIdx.x;
    const int bhi = b * H_ + h;
    const int so  = bhi * N_;
    const int tid = threadIdx.x;

    for (int i = tid; i < N_; i += 512) {
        tS[i]  = tSg[so + i];
        kI[i]  = kIg[so + i];
        e1S[i] = e1g[so + i];
        e2S[i] = e2g[so + i];
    }
    __syncthreads();

    // chunk sums in-block: 512 threads = 512 cells (cc 0..63, dg 0..7)
    {
        const int cc = tid >> 3, dg = tid & 7;
        float4_ a1 = {0.f, 0.f, 0.f, 0.f}, a2 = {0.f, 0.f, 0.f, 0.f};
        #pragma unroll
        for (int jj = 0; jj < CH; ++jj) {
            const int j = cc * CH + jj;
            const float4_ hv = *reinterpret_cast<const float4_*>(
                &h_ws[(size_t)(b * N_ + kI[j]) * IND + h * D_ + dg * 4]);
            a1 += e1S[j] * hv;
            a2 += e2S[j] * hv;
        }
        #pragma unroll
        for (int u = 0; u < 4; ++u) {
            pre2[cc + 1][dg * 4 + u] = a2[u];
            suf1[cc][dg * 4 + u]     = a1[u];
        }
        if (tid < NCH) {
            float s2 = 0.f;
            #pragma unroll
            for (int jj = 0; jj < CH; ++jj) s2 += e2S[tid * CH + jj];
            dpre2[tid + 1] = s2;
        } else if (tid < 2 * NCH) {
            const int c2 = tid - NCH;
            float s1 = 0.f;
            #pragma unroll
            for (int jj = 0; jj < CH; ++jj) s1 += e1S[c2 * CH + jj];
            dsuf1[c2] = s1;
        }
    }
    __syncthreads();

    // in-block scans: waves 0-3 prefix, waves 4-7 suffix
    {
        const int wv = tid >> 6, lane = tid & 63;
        if (wv < 4) {
            for (int d = wv; d < D_; d += 4) {
                float v = pre2[lane + 1][d];
                #pragma unroll
                for (int off = 1; off < 64; off <<= 1) {
                    float n = __shfl_up(v, off);
                    if (lane >= off) v += n;
                }
                pre2[lane + 1][d] = v;
                if (lane == 0) pre2[0][d] = 0.f;
            }
            if (wv == 0) {
                float v = dpre2[lane + 1];
                #pragma unroll
                for (int off = 1; off < 64; off <<= 1) {
                    float n = __shfl_up(v, off);
                    if (lane >= off) v += n;
                }
                dpre2[lane + 1] = v;
                if (lane == 0) dpre2[0] = 0.f;
            }
        } else {
            for (int d = wv - 4; d < D_; d += 4) {
                float v = suf1[lane][d];
                #pragma unroll
                for (int off = 1; off < 64; off <<= 1) {
                    float n = __shfl_down(v, off);
                    if (lane < 64 - off) v += n;
                }
                suf1[lane][d] = v;
                if (lane == 0) { suf1[NCH][d] = 0.f; suf1[NCH + 1][d] = 0.f; }
            }
            if (wv == 4) {
                float v = dsuf1[lane];
                #pragma unroll
                for (int off = 1; off < 64; off <<= 1) {
                    float n = __shfl_down(v, off);
                    if (lane < 64 - off) v += n;
                }
                dsuf1[lane] = v;
                if (lane == 0) { dsuf1[NCH] = 0.f; dsuf1[NCH + 1] = 0.f; }
            }
        }
    }
    __syncthreads();

    const int ql  = tid >> 3;
    const int sub = tid & 7;
    const int ln  = tid & 63;
    const int q   = qb * QB + ql;

    const float s  = sT[h * BN + b * N_ + q];
    const float A  = __expf(s);
    const float Bv = __expf(NEG * s);

    // binary search once per query group (lane sub==0), broadcast via shfl
    int p = 0;
    if (sub == 0) {
        const float tau = -s;
        int lo = 0, hi = N_;
        #pragma unroll
        for (int it = 0; it < 10; ++it) {
            int mid = (lo + hi) >> 1;
            if (tS[mid] >= tau) hi = mid; else lo = mid + 1;
        }
        p = lo;
    }
    p = __shfl(p, ln & 56);
    const int cp = p >> 4;

    // table part + uniform 16-iter boundary-chunk loop (weight select)
    float4_ acc = A  * (*reinterpret_cast<const float4_*>(&suf1[cp + 1][sub * 4]))
                + Bv * (*reinterpret_cast<const float4_*>(&pre2[cp][sub * 4]));
    float den = A * dsuf1[cp + 1] + Bv * dpre2[cp];
    if (cp < NCH) {
        #pragma unroll
        for (int jj = 0; jj < CH; ++jj) {
            const int j = (cp << 4) + jj;
            const float w = (j < p) ? Bv * e2S[j] : A * e1S[j];
            const float4_ hv = *reinterpret_cast<const float4_*>(
                &h_ws[(size_t)(b * N_ + kI[j]) * IND + h * D_ + sub * 4]);
            acc += w * hv;
            den += w;
        }
    }

    const float inv = (den > 0.f) ? 1.f / den : 0.f;
    float4_ r = acc * inv;
    *reinterpret_cast<float4_*>(&out[(size_t)(b * N_ + q) * IND + h * D_ + sub * 4]) = r;
}

extern "C" void kernel_launch(void* const* d_in, const int* in_sizes, int n_in,
                              void* d_out, int out_size, void* d_ws, size_t ws_size,
                              hipStream_t stream) {
    const float* x     = (const float*)d_in[0];
    const float* alive = (const float*)d_in[1];
    const float* W     = (const float*)d_in[2];
    const float* a_src = (const float*)d_in[3];
    const float* a_dst = (const float*)d_in[4];
    float* out = (float*)d_out;

    float* h_ws   = (float*)d_ws;               // BN*128
    float* sT     = h_ws + (size_t)BN * IND;    // [H][BN]
    float* tT     = sT  + (size_t)H_ * BN;
    float* e1T    = tT  + (size_t)H_ * BN;
    float* e2T    = e1T + (size_t)H_ * BN;
    float* tSg    = e2T + (size_t)H_ * BN;      // [32][N]
    int*   kIg    = (int*)(tSg + 32 * N_);
    float* e1g    = (float*)(kIg + 32 * N_);
    float* e2g    = e1g + 32 * N_;              // total ~4.9 MB

    k_gemm_alpha<<<BN / 32, 256, 0, stream>>>(x, alive, W, a_src, a_dst,
                                              h_ws, sT, tT, e1T, e2T);

    dim3 g2(N_ / 128, H_, B_);
    k_rank<<<g2, 256, 0, stream>>>(tT, e1T, e2T, tSg, kIg, e1g, e2g);

    dim3 g4(N_ / QB, H_, B_);
    k_comb<<<g4, 512, 0, stream>>>(h_ws, sT, tSg, kIg, e1g, e2g, out);
}